// Round 1
// baseline (310.157 us; speedup 1.0000x reference)
//
#include <hip/hip_runtime.h>

// ---------------------------------------------------------------------------
// CrossAttention_LocalAVTokens: bs=32, nmm=256, nv=196, na=60 (nv+na=256),
// DIM=768, HEADS=12, hd=64. Outputs: out [32,256,768] f32, attn [32,12,256,256] f32.
// Strategy: fp16 MFMA (16x16x32) everywhere, fp32 accumulate. 2%-of-absmax
// tolerance admits f16 (not bf16).
// ---------------------------------------------------------------------------

typedef __attribute__((ext_vector_type(8))) _Float16 f16x8;
typedef __attribute__((ext_vector_type(4))) _Float16 f16x4;
typedef __attribute__((ext_vector_type(4))) float    f32x4;

#define AS1 __attribute__((address_space(1)))
#define AS3 __attribute__((address_space(3)))

// async global->LDS, 16B per lane. LDS dest is wave-uniform base + lane*16,
// so per-wave lane order must be contiguous in LDS (it is, below).
__device__ __forceinline__ void gload_lds16(const void* g, void* l) {
    void* gnc = const_cast<void*>(g);
    __builtin_amdgcn_global_load_lds((AS1 void*)gnc, (AS3 void*)l, 16, 0, 0);
}

// ---------------------------------------------------------------------------
// Cast kernels
// ---------------------------------------------------------------------------
__global__ __launch_bounds__(256) void cast_f32_f16(const float* __restrict__ in,
                                                    _Float16* __restrict__ out, int n4) {
    int id = blockIdx.x * 256 + threadIdx.x;
    if (id >= n4) return;
    float4 v = ((const float4*)in)[id];
    f16x4 h = { (_Float16)v.x, (_Float16)v.y, (_Float16)v.z, (_Float16)v.w };
    ((f16x4*)out)[id] = h;
}

// concat [xv (196 rows) ; xa (60 rows)] per batch -> xsrc16 [32,256,768] f16
__global__ __launch_bounds__(256) void concat_cast(const float* __restrict__ xv,
                                                   const float* __restrict__ xa,
                                                   _Float16* __restrict__ out) {
    int id = blockIdx.x * 256 + threadIdx.x;   // float4 units; total 1572864
    if (id >= 1572864) return;
    int c4 = id % 192;
    int r  = (id / 192) & 255;
    int b  = id / 49152;
    float4 v;
    if (r < 196) v = ((const float4*)xv)[((long)b * 196 + r) * 192 + c4];
    else         v = ((const float4*)xa)[((long)b * 60 + (r - 196)) * 192 + c4];
    f16x4 h = { (_Float16)v.x, (_Float16)v.y, (_Float16)v.z, (_Float16)v.w };
    ((f16x4*)out)[id] = h;
}

// out[n*K + k] = (f16) in[k*N + n]   (weights are small; L2 absorbs the stride)
__global__ __launch_bounds__(256) void transcast(const float* __restrict__ in,
                                                 _Float16* __restrict__ out, int K, int N) {
    int id = blockIdx.x * 256 + threadIdx.x;
    if (id >= K * N) return;
    int k = id % K, n = id / K;
    out[id] = (_Float16)in[(long)k * N + n];
}

// ---------------------------------------------------------------------------
// GEMM: C[M,N] = A[M,K] @ Bt[N,K]^T   (f16 inputs, f32 accumulate)
// 128x128 tile, BK=64, 256 threads (4 waves, each 64x64 = 4x4 MFMA tiles).
// LDS XOR-swizzled at 16B-block granularity to kill row-stride bank aliasing.
// ---------------------------------------------------------------------------
template <int OUT_F32>
__global__ __launch_bounds__(256, 2)
void gemm_bt(const _Float16* __restrict__ A, const _Float16* __restrict__ Bt,
             void* __restrict__ C, const float* __restrict__ bias,
             int M, int N, int K) {
    __shared__ _Float16 As[128 * 64];
    __shared__ _Float16 Bs[128 * 64];

    const int tid  = threadIdx.x;
    const int wave = tid >> 6, lane = tid & 63;
    const int lrow = lane & 15, quad = lane >> 4;
    const long bm = (long)blockIdx.y * 128, bn = (long)blockIdx.x * 128;
    const int wm = (wave >> 1) * 64, wn = (wave & 1) * 64;

    f32x4 acc[4][4];
    const f32x4 fz = {0.f, 0.f, 0.f, 0.f};
#pragma unroll
    for (int mt = 0; mt < 4; ++mt)
#pragma unroll
        for (int nt = 0; nt < 4; ++nt) acc[mt][nt] = fz;

    for (int k0 = 0; k0 < K; k0 += 64) {
#pragma unroll
        for (int it = 0; it < 4; ++it) {
            int seg = tid + it * 256;                 // 1024 segs of 8 halves
            int rr = seg >> 3, pp = seg & 7;
            int cc = ((pp ^ (rr & 7)) << 3);          // swizzled source column
            gload_lds16(A  + (bm + rr) * (long)K + k0 + cc, As + seg * 8);
            gload_lds16(Bt + (bn + rr) * (long)K + k0 + cc, Bs + seg * 8);
        }
        __syncthreads();   // drains vmcnt -> LDS tiles valid
#pragma unroll
        for (int ks = 0; ks < 2; ++ks) {
            f16x8 af[4], bf[4];
#pragma unroll
            for (int mt = 0; mt < 4; ++mt) {
                int r = wm + mt * 16 + lrow;
                af[mt] = *(const f16x8*)(As + r * 64 + (((ks * 4 + quad) ^ (r & 7)) << 3));
            }
#pragma unroll
            for (int nt = 0; nt < 4; ++nt) {
                int r = wn + nt * 16 + lrow;
                bf[nt] = *(const f16x8*)(Bs + r * 64 + (((ks * 4 + quad) ^ (r & 7)) << 3));
            }
#pragma unroll
            for (int mt = 0; mt < 4; ++mt)
#pragma unroll
                for (int nt = 0; nt < 4; ++nt)
                    acc[mt][nt] = __builtin_amdgcn_mfma_f32_16x16x32_f16(
                        af[mt], bf[nt], acc[mt][nt], 0, 0, 0);
        }
        __syncthreads();
    }

    // epilogue: C/D layout col=lane&15, row=quad*4+reg
#pragma unroll
    for (int mt = 0; mt < 4; ++mt) {
#pragma unroll
        for (int j = 0; j < 4; ++j) {
            long row = bm + wm + mt * 16 + quad * 4 + j;
#pragma unroll
            for (int nt = 0; nt < 4; ++nt) {
                long col = bn + wn + nt * 16 + lrow;
                float v = acc[mt][nt][j];
                if (OUT_F32) ((float*)C)[row * N + col] = v + bias[col];
                else         ((_Float16*)C)[row * N + col] = (_Float16)v;
            }
        }
    }
}

// ---------------------------------------------------------------------------
// Fused attention: one WG per (qblock=64 rows, head, batch) = (4,12,32).
// 4 waves; wave w owns query rows [16w,16w+16). Full K (256 keys) per WG.
// LDS (64 KB): Ks [256][64] (swizzled) | Vt [64][256] transposed+swizzled.
// Ps [64][256] (swizzled) aliases Ks after the S phase.
// ---------------------------------------------------------------------------
__global__ __launch_bounds__(256, 2)
void attn_kernel(const _Float16* __restrict__ Qg, const _Float16* __restrict__ KVg,
                 float* __restrict__ attn_out, _Float16* __restrict__ Og) {
    __shared__ _Float16 sh[32768];          // 64 KB
    _Float16* Ks = sh;                      // 16384 halves
    _Float16* Vt = sh + 16384;              // 16384 halves
    _Float16* Ps = sh;                      // aliases Ks (after barrier)

    const int tid  = threadIdx.x;
    const int wave = tid >> 6, lane = tid & 63;
    const int lrow = lane & 15, quad = lane >> 4;
    const int qb = blockIdx.x, h = blockIdx.y, b = blockIdx.z;
    const long qrow0 = (long)b * 256 + qb * 64;
    const long krow0 = (long)b * 256;

    // Q fragments straight from global (A layout: m=lane&15, k=quad*8+j)
    f16x8 aq[2];
#pragma unroll
    for (int ks = 0; ks < 2; ++ks)
        aq[ks] = *(const f16x8*)(Qg + (qrow0 + wave * 16 + lrow) * 768 + h * 64 + ks * 32 + quad * 8);

    // K -> LDS (async, swizzled): KV layout col = h*64+d (K half)
#pragma unroll
    for (int it = 0; it < 8; ++it) {
        int seg = tid + it * 256;
        int rr = seg >> 3, pp = seg & 7;
        int cc = ((pp ^ (rr & 7)) << 3);
        gload_lds16(KVg + (krow0 + rr) * 1536 + h * 64 + cc, Ks + seg * 8);
    }
    // V -> LDS transposed (B operand needs V^T[d][key]); swizzled 16B blocks
#pragma unroll
    for (int it = 0; it < 8; ++it) {
        int seg = tid + it * 256;
        int key = seg >> 3, d0 = (seg & 7) * 8;
        f16x8 v = *(const f16x8*)(KVg + (krow0 + key) * 1536 + 768 + h * 64 + d0);
#pragma unroll
        for (int i = 0; i < 8; ++i) {
            int d = d0 + i;
            Vt[d * 256 + ((((key >> 3) ^ (d & 7)) << 3) | (key & 7))] = v[i];
        }
    }
    __syncthreads();

    // S = Q K^T  (per wave: 16 rows x 256 keys = 16 n-tiles)
    f32x4 sacc[16];
    const f32x4 fz = {0.f, 0.f, 0.f, 0.f};
#pragma unroll
    for (int nt = 0; nt < 16; ++nt) sacc[nt] = fz;
#pragma unroll
    for (int ks = 0; ks < 2; ++ks) {
#pragma unroll
        for (int nt = 0; nt < 16; ++nt) {
            int r = nt * 16 + lrow;
            f16x8 bk = *(const f16x8*)(Ks + r * 64 + (((ks * 4 + quad) ^ (r & 7)) << 3));
            sacc[nt] = __builtin_amdgcn_mfma_f32_16x16x32_f16(aq[ks], bk, sacc[nt], 0, 0, 0);
        }
    }

    // softmax: lane holds rows (quad*4+j) of the wave strip, cols nt*16+lrow.
    // Row lives in the 16 lanes sharing `quad` -> shfl_xor masks 1,2,4,8.
    float li[4];
#pragma unroll
    for (int j = 0; j < 4; ++j) {
        float m = -1e30f;
#pragma unroll
        for (int nt = 0; nt < 16; ++nt) { sacc[nt][j] *= 0.125f; m = fmaxf(m, sacc[nt][j]); }
        m = fmaxf(m, __shfl_xor(m, 1));
        m = fmaxf(m, __shfl_xor(m, 2));
        m = fmaxf(m, __shfl_xor(m, 4));
        m = fmaxf(m, __shfl_xor(m, 8));
        float s = 0.f;
#pragma unroll
        for (int nt = 0; nt < 16; ++nt) {
            float p = __expf(sacc[nt][j] - m);
            sacc[nt][j] = p; s += p;
        }
        s += __shfl_xor(s, 1); s += __shfl_xor(s, 2);
        s += __shfl_xor(s, 4); s += __shfl_xor(s, 8);
        li[j] = 1.f / s;
    }
    __syncthreads();   // all waves done reading Ks before Ps overwrites it

    // write attn (fp32, from registers) + stage P (f16) into LDS for PV
    const long abase = (((long)b * 12 + h) * 256 + qb * 64) * 256;
#pragma unroll
    for (int j = 0; j < 4; ++j) {
        int prow = wave * 16 + quad * 4 + j;
#pragma unroll
        for (int nt = 0; nt < 16; ++nt) {
            int col = nt * 16 + lrow;
            float p = sacc[nt][j];
            Ps[prow * 256 + ((((col >> 3) ^ (prow & 7)) << 3) | (col & 7))] = (_Float16)p;
            attn_out[abase + (long)prow * 256 + col] = p * li[j];
        }
    }
    __syncthreads();

    // O = P V   (K-dim = 256 keys -> 8 MFMA k-steps; 4 d-tiles)
    f32x4 oacc[4];
#pragma unroll
    for (int nt = 0; nt < 4; ++nt) oacc[nt] = fz;
#pragma unroll
    for (int ks = 0; ks < 8; ++ks) {
        int pr = wave * 16 + lrow;
        f16x8 ap = *(const f16x8*)(Ps + pr * 256 + (((ks * 4 + quad) ^ (pr & 7)) << 3));
#pragma unroll
        for (int nt = 0; nt < 4; ++nt) {
            int d = nt * 16 + lrow;
            f16x8 bv = *(const f16x8*)(Vt + d * 256 + (((ks * 4 + quad) ^ (d & 7)) << 3));
            oacc[nt] = __builtin_amdgcn_mfma_f32_16x16x32_f16(ap, bv, oacc[nt], 0, 0, 0);
        }
    }
    // epilogue rows = wave*16 + quad*4 + j -> same rows li[j] was computed for
#pragma unroll
    for (int j = 0; j < 4; ++j) {
        long orow = qrow0 + wave * 16 + quad * 4 + j;
#pragma unroll
        for (int nt = 0; nt < 4; ++nt)
            Og[orow * 768 + h * 64 + nt * 16 + lrow] = (_Float16)(oacc[nt][j] * li[j]);
    }
}

// ---------------------------------------------------------------------------
extern "C" void kernel_launch(void* const* d_in, const int* in_sizes, int n_in,
                              void* d_out, int out_size, void* d_ws, size_t ws_size,
                              hipStream_t stream) {
    const float* xmm   = (const float*)d_in[0];  // [32,256,768]
    const float* xv    = (const float*)d_in[1];  // [32,196,768]
    const float* xa    = (const float*)d_in[2];  // [32, 60,768]
    const float* Wq    = (const float*)d_in[3];  // [768,768]
    const float* Wkv   = (const float*)d_in[4];  // [768,1536]
    const float* Wproj = (const float*)d_in[5];  // [768,768]
    const float* bproj = (const float*)d_in[6];  // [768]

    float* out  = (float*)d_out;            // [32,256,768] = 6291456
    float* attn = out + 6291456;            // [32,12,256,256] = 25165824

    char* ws = (char*)d_ws;
    _Float16* xmm16  = (_Float16*)(ws);                   // 12,582,912 B
    _Float16* xsrc16 = (_Float16*)(ws + 12582912);        // 12,582,912 B
    _Float16* WqT    = (_Float16*)(ws + 25165824);        //  1,179,648 B
    _Float16* WkvT   = (_Float16*)(ws + 26345472);        //  2,359,296 B
    _Float16* WprojT = (_Float16*)(ws + 28704768);        //  1,179,648 B
    _Float16* Q16    = (_Float16*)(ws + 29884416);        // 12,582,912 B
    _Float16* KV16   = (_Float16*)(ws + 42467328);        // 25,165,824 B
    _Float16* O16    = xmm16;  // xmm16 dead after GEMM1; reuse for O (pre-proj)
    // total ws use: 67,633,152 B

    cast_f32_f16<<<6144, 256, 0, stream>>>(xmm, xmm16, 1572864);
    concat_cast <<<6144, 256, 0, stream>>>(xv, xa, xsrc16);
    transcast   <<<2304, 256, 0, stream>>>(Wq,    WqT,    768, 768);
    transcast   <<<4608, 256, 0, stream>>>(Wkv,   WkvT,   768, 1536);
    transcast   <<<2304, 256, 0, stream>>>(Wproj, WprojT, 768, 768);

    gemm_bt<0><<<dim3(6, 64),  256, 0, stream>>>(xmm16,  WqT,  (void*)Q16,  nullptr, 8192, 768,  768);
    gemm_bt<0><<<dim3(12, 64), 256, 0, stream>>>(xsrc16, WkvT, (void*)KV16, nullptr, 8192, 1536, 768);

    attn_kernel<<<dim3(4, 12, 32), 256, 0, stream>>>(Q16, KV16, attn, O16);

    gemm_bt<1><<<dim3(6, 64),  256, 0, stream>>>(O16, WprojT, (void*)out, bproj, 8192, 768, 768);
}

// Round 2
// 298.947 us; speedup vs baseline: 1.0375x; 1.0375x over previous
//
#include <hip/hip_runtime.h>

// ---------------------------------------------------------------------------
// CrossAttention_LocalAVTokens: bs=32, nmm=256, nv=196, na=60 (nv+na=256),
// DIM=768, HEADS=12, hd=64. Outputs: out [32,256,768] f32, attn [32,12,256,256] f32.
// fp16 MFMA 16x16x32, fp32 accumulate. Round 2: operand-swapped MFMA so every
// epilogue is vectorized (lane holds 4 consecutive columns), merged QKV GEMM,
// merged cast kernels, softmax scale folded into Wq.
// ---------------------------------------------------------------------------

typedef __attribute__((ext_vector_type(8))) _Float16 f16x8;
typedef __attribute__((ext_vector_type(4))) _Float16 f16x4;
typedef __attribute__((ext_vector_type(4))) float    f32x4;

#define AS1 __attribute__((address_space(1)))
#define AS3 __attribute__((address_space(3)))

__device__ __forceinline__ void gload_lds16(const void* g, void* l) {
    void* gnc = const_cast<void*>(g);
    __builtin_amdgcn_global_load_lds((AS1 void*)gnc, (AS3 void*)l, 16, 0, 0);
}

// ---------------------------------------------------------------------------
// prep_acts: cast xmm -> f16, concat+cast [xv;xa] -> f16. float4 granularity.
// ---------------------------------------------------------------------------
__global__ __launch_bounds__(256) void prep_acts(const float* __restrict__ xmm,
                                                 const float* __restrict__ xv,
                                                 const float* __restrict__ xa,
                                                 _Float16* __restrict__ xmm16,
                                                 _Float16* __restrict__ xsrc16) {
    int id = blockIdx.x * 256 + threadIdx.x;          // 2 * 1572864 float4s
    float4 v;
    _Float16* dst;
    int off;
    if (id < 1572864) {
        v = ((const float4*)xmm)[id];
        dst = xmm16; off = id;
    } else {
        int t = id - 1572864;
        int c4 = t % 192;
        int r  = (t / 192) & 255;
        int b  = t / 49152;
        if (r < 196) v = ((const float4*)xv)[((long)b * 196 + r) * 192 + c4];
        else         v = ((const float4*)xa)[((long)b * 60 + (r - 196)) * 192 + c4];
        dst = xsrc16; off = t;
    }
    f16x4 h = { (_Float16)v.x, (_Float16)v.y, (_Float16)v.z, (_Float16)v.w };
    ((f16x4*)dst)[off] = h;
}

// ---------------------------------------------------------------------------
// prep_weights: transpose+cast all three weights; fold 0.125 (hd^-0.5) into Wq.
// ---------------------------------------------------------------------------
__global__ __launch_bounds__(256) void prep_weights(const float* __restrict__ Wq,
                                                    const float* __restrict__ Wkv,
                                                    const float* __restrict__ Wproj,
                                                    _Float16* __restrict__ WqT,
                                                    _Float16* __restrict__ WkvT,
                                                    _Float16* __restrict__ WprojT) {
    int id = blockIdx.x * 256 + threadIdx.x;
    if (id < 589824) {            // WqT [768n][768k] = 0.125 * Wq[k][n]
        int k = id % 768, n = id / 768;
        WqT[id] = (_Float16)(0.125f * Wq[(long)k * 768 + n]);
        return;
    }
    id -= 589824;
    if (id < 1179648) {           // WkvT [1536n][768k]
        int k = id % 768, n = id / 768;
        WkvT[id] = (_Float16)Wkv[(long)k * 1536 + n];
        return;
    }
    id -= 1179648;
    if (id < 589824) {            // WprojT [768n][768k]
        int k = id % 768, n = id / 768;
        WprojT[id] = (_Float16)Wproj[(long)k * 768 + n];
    }
}

// ---------------------------------------------------------------------------
// Shared GEMM body: C[M,N] = A[M,K] @ Bt[N,K]^T, 128x128 tile, BK=64, 4 waves.
// mfma(bf, af) => lane holds C[row=..+lrow][col=..+quad*4+{0..3}] -> vector stores.
// ---------------------------------------------------------------------------
template <int OUT_F32>
__device__ __forceinline__ void gemm_body(const _Float16* __restrict__ A,
                                          const _Float16* __restrict__ Bt,
                                          void* __restrict__ C,
                                          const float* __restrict__ bias,
                                          long bm, long bn, int N, int K) {
    __shared__ _Float16 As[128 * 64];
    __shared__ _Float16 Bs[128 * 64];

    const int tid  = threadIdx.x;
    const int wave = tid >> 6, lane = tid & 63;
    const int lrow = lane & 15, quad = lane >> 4;
    const int wm = (wave >> 1) * 64, wn = (wave & 1) * 64;

    f32x4 acc[4][4];
    const f32x4 fz = {0.f, 0.f, 0.f, 0.f};
#pragma unroll
    for (int mt = 0; mt < 4; ++mt)
#pragma unroll
        for (int nt = 0; nt < 4; ++nt) acc[mt][nt] = fz;

    for (int k0 = 0; k0 < K; k0 += 64) {
#pragma unroll
        for (int it = 0; it < 4; ++it) {
            int seg = tid + it * 256;                 // 1024 segs of 8 halves
            int rr = seg >> 3, pp = seg & 7;
            int cc = ((pp ^ (rr & 7)) << 3);          // swizzled source column
            gload_lds16(A  + (bm + rr) * (long)K + k0 + cc, As + seg * 8);
            gload_lds16(Bt + (bn + rr) * (long)K + k0 + cc, Bs + seg * 8);
        }
        __syncthreads();
#pragma unroll
        for (int ks = 0; ks < 2; ++ks) {
            f16x8 af[4], bf[4];
#pragma unroll
            for (int mt = 0; mt < 4; ++mt) {
                int r = wm + mt * 16 + lrow;
                af[mt] = *(const f16x8*)(As + r * 64 + (((ks * 4 + quad) ^ (r & 7)) << 3));
            }
#pragma unroll
            for (int nt = 0; nt < 4; ++nt) {
                int r = wn + nt * 16 + lrow;
                bf[nt] = *(const f16x8*)(Bs + r * 64 + (((ks * 4 + quad) ^ (r & 7)) << 3));
            }
#pragma unroll
            for (int mt = 0; mt < 4; ++mt)
#pragma unroll
                for (int nt = 0; nt < 4; ++nt)
                    acc[mt][nt] = __builtin_amdgcn_mfma_f32_16x16x32_f16(
                        bf[nt], af[mt], acc[mt][nt], 0, 0, 0);   // swapped: D = C^T tile
        }
        __syncthreads();
    }

    // epilogue: lane owns C[bm+wm+mt*16+lrow][bn+wn+nt*16+quad*4 + 0..3]
#pragma unroll
    for (int mt = 0; mt < 4; ++mt) {
        long row = bm + wm + mt * 16 + lrow;
#pragma unroll
        for (int nt = 0; nt < 4; ++nt) {
            long col0 = bn + wn + nt * 16 + quad * 4;
            if (OUT_F32) {
                float4 b4 = *(const float4*)(bias + col0);
                float4 o = { acc[mt][nt][0] + b4.x, acc[mt][nt][1] + b4.y,
                             acc[mt][nt][2] + b4.z, acc[mt][nt][3] + b4.w };
                *(float4*)((float*)C + row * N + col0) = o;
            } else {
                f16x4 h = { (_Float16)acc[mt][nt][0], (_Float16)acc[mt][nt][1],
                            (_Float16)acc[mt][nt][2], (_Float16)acc[mt][nt][3] };
                *(f16x4*)((_Float16*)C + row * N + col0) = h;
            }
        }
    }
}

// Merged Q + KV projection: grid (6+12, 64). bx<6 -> Q, else KV.
__global__ __launch_bounds__(256, 2)
void gemm_qkv(const _Float16* __restrict__ xmm16, const _Float16* __restrict__ xsrc16,
              const _Float16* __restrict__ WqT, const _Float16* __restrict__ WkvT,
              _Float16* __restrict__ Q16, _Float16* __restrict__ KV16) {
    const int bx = blockIdx.x;
    const long bm = (long)blockIdx.y * 128;
    if (bx < 6) gemm_body<0>(xmm16,  WqT,  (void*)Q16,  nullptr, bm, (long)bx * 128,       768,  768);
    else        gemm_body<0>(xsrc16, WkvT, (void*)KV16, nullptr, bm, (long)(bx - 6) * 128, 1536, 768);
}

// Output projection (+bias), f32 out. grid (6, 64).
__global__ __launch_bounds__(256, 2)
void gemm_proj(const _Float16* __restrict__ O16, const _Float16* __restrict__ WprojT,
               float* __restrict__ out, const float* __restrict__ bias) {
    gemm_body<1>(O16, WprojT, (void*)out, bias, (long)blockIdx.y * 128, (long)blockIdx.x * 128, 768, 768);
}

// ---------------------------------------------------------------------------
// Fused attention: WG = (qblock=64 q-rows, head, batch) = (4,12,32) grid.
// LDS: Ks[256][64] swz | Vt[64][256] swz; Ps[64][256] swz aliases Ks.
// S computed transposed (mfma(bk,aq)): lane holds q=wave*16+lrow fixed,
// keys nt*16+quad*4+{0..3} -> softmax needs only shfl_xor 16,32.
// ---------------------------------------------------------------------------
__global__ __launch_bounds__(256, 2)
void attn_kernel(const _Float16* __restrict__ Qg, const _Float16* __restrict__ KVg,
                 float* __restrict__ attn_out, _Float16* __restrict__ Og) {
    __shared__ _Float16 sh[32768];          // 64 KB
    _Float16* Ks = sh;
    _Float16* Vt = sh + 16384;
    _Float16* Ps = sh;                      // aliases Ks after S phase

    const int tid  = threadIdx.x;
    const int wave = tid >> 6, lane = tid & 63;
    const int lrow = lane & 15, quad = lane >> 4;
    const int qb = blockIdx.x, h = blockIdx.y, b = blockIdx.z;
    const long qrow0 = (long)b * 256 + qb * 64;
    const long krow0 = (long)b * 256;

    // Q fragments from global (A layout: idx=lane&15 -> q, k=quad*8+j)
    f16x8 aq[2];
#pragma unroll
    for (int ks = 0; ks < 2; ++ks)
        aq[ks] = *(const f16x8*)(Qg + (qrow0 + wave * 16 + lrow) * 768 + h * 64 + ks * 32 + quad * 8);

    // K -> LDS async, swizzled
#pragma unroll
    for (int it = 0; it < 8; ++it) {
        int seg = tid + it * 256;
        int rr = seg >> 3, pp = seg & 7;
        int cc = ((pp ^ (rr & 7)) << 3);
        gload_lds16(KVg + (krow0 + rr) * 1536 + h * 64 + cc, Ks + seg * 8);
    }
    // V -> LDS transposed (V^T[d][key]), swizzled 16B blocks
#pragma unroll
    for (int it = 0; it < 8; ++it) {
        int seg = tid + it * 256;
        int key = seg >> 3, d0 = (seg & 7) * 8;
        f16x8 v = *(const f16x8*)(KVg + (krow0 + key) * 1536 + 768 + h * 64 + d0);
#pragma unroll
        for (int i = 0; i < 8; ++i) {
            int d = d0 + i;
            Vt[d * 256 + ((((key >> 3) ^ (d & 7)) << 3) | (key & 7))] = v[i];
        }
    }
    __syncthreads();

    // S^T = K Q^T : sacc[nt] lane holds keys nt*16+quad*4+{0..3}, q=wave*16+lrow
    f32x4 sacc[16];
    const f32x4 fz = {0.f, 0.f, 0.f, 0.f};
#pragma unroll
    for (int nt = 0; nt < 16; ++nt) sacc[nt] = fz;
#pragma unroll
    for (int ks = 0; ks < 2; ++ks) {
#pragma unroll
        for (int nt = 0; nt < 16; ++nt) {
            int r = nt * 16 + lrow;
            f16x8 bk = *(const f16x8*)(Ks + r * 64 + (((ks * 4 + quad) ^ (r & 7)) << 3));
            sacc[nt] = __builtin_amdgcn_mfma_f32_16x16x32_f16(bk, aq[ks], sacc[nt], 0, 0, 0);
        }
    }

    // softmax over keys for q=wave*16+lrow: 64 in-lane + quads (shfl 16,32).
    // scale (0.125) already folded into Wq.
    float m = -1e30f;
#pragma unroll
    for (int nt = 0; nt < 16; ++nt)
#pragma unroll
        for (int j = 0; j < 4; ++j) m = fmaxf(m, sacc[nt][j]);
    m = fmaxf(m, __shfl_xor(m, 16));
    m = fmaxf(m, __shfl_xor(m, 32));
    float s = 0.f;
#pragma unroll
    for (int nt = 0; nt < 16; ++nt)
#pragma unroll
        for (int j = 0; j < 4; ++j) {
            float p = __expf(sacc[nt][j] - m);
            sacc[nt][j] = p; s += p;
        }
    s += __shfl_xor(s, 16);
    s += __shfl_xor(s, 32);
    const float li = 1.f / s;

    __syncthreads();   // all waves done reading Ks before Ps overwrites it

    // write attn (float4) + stage normalized P (f16x4) into LDS
    const long abase = (((long)b * 12 + h) * 256 + qb * 64) * 256;
    const int q = wave * 16 + lrow;
#pragma unroll
    for (int nt = 0; nt < 16; ++nt) {
        float4 o = { sacc[nt][0] * li, sacc[nt][1] * li, sacc[nt][2] * li, sacc[nt][3] * li };
        *(float4*)(attn_out + abase + (long)q * 256 + nt * 16 + quad * 4) = o;
        f16x4 hp = { (_Float16)o.x, (_Float16)o.y, (_Float16)o.z, (_Float16)o.w };
        int blk = nt * 2 + (quad >> 1);
        *(f16x4*)(Ps + q * 256 + ((blk ^ (q & 7)) << 3) + ((quad & 1) << 2)) = hp;
    }
    __syncthreads();

    // O = P V : mfma(bv, ap) -> lane holds d=nt*16+quad*4+{0..3}, q=wave*16+lrow
    f32x4 oacc[4];
#pragma unroll
    for (int nt = 0; nt < 4; ++nt) oacc[nt] = fz;
#pragma unroll
    for (int ks = 0; ks < 8; ++ks) {
        int pr = wave * 16 + lrow;
        f16x8 ap = *(const f16x8*)(Ps + pr * 256 + (((ks * 4 + quad) ^ (pr & 7)) << 3));
#pragma unroll
        for (int nt = 0; nt < 4; ++nt) {
            int d = nt * 16 + lrow;
            f16x8 bv = *(const f16x8*)(Vt + d * 256 + (((ks * 4 + quad) ^ (d & 7)) << 3));
            oacc[nt] = __builtin_amdgcn_mfma_f32_16x16x32_f16(bv, ap, oacc[nt], 0, 0, 0);
        }
    }
#pragma unroll
    for (int nt = 0; nt < 4; ++nt) {
        f16x4 ho = { (_Float16)oacc[nt][0], (_Float16)oacc[nt][1],
                     (_Float16)oacc[nt][2], (_Float16)oacc[nt][3] };
        *(f16x4*)(Og + (qrow0 + wave * 16 + lrow) * 768 + h * 64 + nt * 16 + quad * 4) = ho;
    }
}

// ---------------------------------------------------------------------------
extern "C" void kernel_launch(void* const* d_in, const int* in_sizes, int n_in,
                              void* d_out, int out_size, void* d_ws, size_t ws_size,
                              hipStream_t stream) {
    const float* xmm   = (const float*)d_in[0];  // [32,256,768]
    const float* xv    = (const float*)d_in[1];  // [32,196,768]
    const float* xa    = (const float*)d_in[2];  // [32, 60,768]
    const float* Wq    = (const float*)d_in[3];  // [768,768]
    const float* Wkv   = (const float*)d_in[4];  // [768,1536]
    const float* Wproj = (const float*)d_in[5];  // [768,768]
    const float* bproj = (const float*)d_in[6];  // [768]

    float* out  = (float*)d_out;            // [32,256,768]
    float* attn = out + 6291456;            // [32,12,256,256]

    char* ws = (char*)d_ws;
    _Float16* xmm16  = (_Float16*)(ws);                   // 12,582,912 B
    _Float16* xsrc16 = (_Float16*)(ws + 12582912);        // 12,582,912 B
    _Float16* WqT    = (_Float16*)(ws + 25165824);        //  1,179,648 B
    _Float16* WkvT   = (_Float16*)(ws + 26345472);        //  2,359,296 B
    _Float16* WprojT = (_Float16*)(ws + 28704768);        //  1,179,648 B
    _Float16* Q16    = (_Float16*)(ws + 29884416);        // 12,582,912 B
    _Float16* KV16   = (_Float16*)(ws + 42467328);        // 25,165,824 B
    _Float16* O16    = xmm16;   // xmm16 dead after QKV GEMM; reuse for O

    prep_acts   <<<12288, 256, 0, stream>>>(xmm, xv, xa, xmm16, xsrc16);
    prep_weights<<<9216,  256, 0, stream>>>(Wq, Wkv, Wproj, WqT, WkvT, WprojT);

    gemm_qkv<<<dim3(18, 64), 256, 0, stream>>>(xmm16, xsrc16, WqT, WkvT, Q16, KV16);

    attn_kernel<<<dim3(4, 12, 32), 256, 0, stream>>>(Q16, KV16, attn, O16);

    gemm_proj<<<dim3(6, 64), 256, 0, stream>>>(O16, WprojT, out, bproj);
}